// Round 5
// baseline (624.790 us; speedup 1.0000x reference)
//
#include <hip/hip_runtime.h>
#include <hip/hip_bf16.h>

#define DIM   384
#define NH    12
#define HD    32
#define BATCH 32
#define HH    56
#define WW_   56
#define LTOK  3136
#define MTOK  100352
#define KDIM  384

// LDS row stride (halves) for P and V^T buffers: >=64 extent, bank-even b128
#define PST   68

typedef __attribute__((ext_vector_type(8))) short          bf16x8;
typedef __attribute__((ext_vector_type(8))) _Float16       f16x8;
typedef __attribute__((ext_vector_type(8))) unsigned short u16x8;
typedef __attribute__((ext_vector_type(4))) float          f32x4;
typedef __attribute__((ext_vector_type(4))) unsigned short u16x4;

static __device__ __forceinline__ unsigned short f2bf(float f) {
    __hip_bfloat16 h = __float2bfloat16(f);
    unsigned short u; __builtin_memcpy(&u, &h, 2); return u;
}
static __device__ __forceinline__ float bf2f(unsigned short s) {
    unsigned int u = ((unsigned int)s) << 16;
    float f; __builtin_memcpy(&f, &u, 4); return f;
}

static __device__ __forceinline__ void async_cp16(const unsigned short* g, unsigned short* l) {
    __builtin_amdgcn_global_load_lds((const __attribute__((address_space(1))) void*)g,
                                     (__attribute__((address_space(3))) void*)l, 16, 0, 0);
}

// ---- fp32 -> bf16 bulk convert (x) ----
__global__ __launch_bounds__(256) void cvt_x_kernel(const float* __restrict__ in,
                                                    unsigned short* __restrict__ out, int n4) {
    int i = blockIdx.x * 256 + threadIdx.x;
    if (i >= n4) return;
    f32x4 v = *(const f32x4*)(in + 4 * (size_t)i);
    u16x4 u;
    u[0] = f2bf(v[0]); u[1] = f2bf(v[1]); u[2] = f2bf(v[2]); u[3] = f2bf(v[3]);
    *(u16x4*)(out + 4 * (size_t)i) = u;
}

__global__ __launch_bounds__(256) void cvt_w_kernel(const float* __restrict__ qw,
                                                    const float* __restrict__ pw,
                                                    unsigned short* __restrict__ qwb,
                                                    unsigned short* __restrict__ pwb) {
    int i = blockIdx.x * 256 + threadIdx.x;
    if (i < 3 * DIM * DIM) {
        qwb[i] = f2bf(qw[i]);
    } else {
        int j = i - 3 * DIM * DIM;
        if (j < DIM * DIM) pwb[j] = f2bf(pw[j]);
    }
}

// ---- LDS-staged GEMM: C[M,N] = A[M,384] @ W[N,384]^T + bias ----
// m201-geometry port: BM=512, BN=128, BK=32, 512 threads = 8 waves (4m x 2n),
// wave-tile 128x64 (12 ds_read_b128 : 32 MFMA per K-tile = 0.375, vs 0.5 before).
// Double-buffered LDS (80 KB), stage-ahead-1; per K-tile two MFMA clusters of 16
// wrapped in raw s_barrier + setprio (scheduling only; intra-tile LDS is read-only
// so these barriers carry no correctness weight). The only full drain is the
// end-of-tile __syncthreads, whose in-flight loads are a whole K-tile old.
// Bijective XCD swizzle (m204) since grid % 8 != 0.
template<bool OUT_BF16>
__global__ __launch_bounds__(512, 2) void gemm_bt(const unsigned short* __restrict__ A,
                                                  const unsigned short* __restrict__ W,
                                                  const float* __restrict__ bias,
                                                  void* __restrict__ Cout,
                                                  int N, int nbn) {
    __shared__ unsigned short ldsA[2][512 * 32];   // 32 KB per buffer
    __shared__ unsigned short ldsB[2][128 * 32];   // 8 KB per buffer

    const int tid   = threadIdx.x;
    const int lane  = tid & 63;
    const int wave  = tid >> 6;          // 0..7
    const int wm    = wave >> 1;         // 0..3 -> m offset wm*128
    const int wn    = wave & 1;          // 0..1 -> n offset wn*64
    const int row16 = lane & 15, quad = lane >> 4;

    // bijective XCD-chunked swizzle (works for any gridDim.x)
    const int nwg = gridDim.x;
    const int qq  = nwg >> 3, rr = nwg & 7;
    const int xcd = blockIdx.x & 7, bidx = blockIdx.x >> 3;
    const int wg  = (xcd < rr ? xcd * (qq + 1) : rr * (qq + 1) + (xcd - rr) * qq) + bidx;

    const int mt = wg / nbn, nt = wg % nbn;
    const int m_base = mt * 512, n_base = nt * 128;

    const unsigned short* Abase = A + (size_t)m_base * KDIM;
    const unsigned short* Wbase = W + (size_t)n_base * KDIM;

    // staging maps: rows have 4 16B-chunks (BK=32); chunk slot XOR (row&3)
    int sArow[4], sAkc[4];
    #pragma unroll
    for (int i = 0; i < 4; i++) {
        int c = i * 512 + tid;           // A chunk 0..2047
        sArow[i] = c >> 2;
        sAkc[i]  = (c & 3) ^ (sArow[i] & 3);
    }
    const int sBrow = tid >> 2;          // B chunk = tid (0..511)
    const int sBkc  = (tid & 3) ^ (sBrow & 3);

    f32x4 acc[8][4] = {};

    #define STAGE(buf, kt)                                                              \
        {                                                                               \
            const int k0 = (kt) * 32;                                                   \
            _Pragma("unroll")                                                           \
            for (int i = 0; i < 4; i++)                                                 \
                async_cp16(Abase + (size_t)sArow[i] * KDIM + k0 + sAkc[i] * 8,          \
                           ldsA[buf] + (i * 512 + wave * 64) * 8);                      \
            async_cp16(Wbase + (size_t)sBrow * KDIM + k0 + sBkc * 8,                    \
                       ldsB[buf] + (wave * 64) * 8);                                    \
        }

    #define COMPUTE(buf)                                                                \
        {                                                                               \
            bf16x8 a[8], b[4];                                                          \
            _Pragma("unroll")                                                           \
            for (int i = 0; i < 4; i++) {                                               \
                const int rowa = wm * 128 + i * 16 + row16;                             \
                a[i] = *(const bf16x8*)(ldsA[buf] + rowa * 32 + ((quad ^ (rowa & 3)) * 8)); \
            }                                                                           \
            _Pragma("unroll")                                                           \
            for (int j = 0; j < 4; j++) {                                               \
                const int rowb = wn * 64 + j * 16 + row16;                              \
                b[j] = *(const bf16x8*)(ldsB[buf] + rowb * 32 + ((quad ^ (rowb & 3)) * 8)); \
            }                                                                           \
            __builtin_amdgcn_s_barrier();                                               \
            __builtin_amdgcn_s_setprio(1);                                              \
            _Pragma("unroll")                                                           \
            for (int i = 0; i < 4; i++)                                                 \
                _Pragma("unroll")                                                       \
                for (int j = 0; j < 4; j++)                                             \
                    acc[i][j] = __builtin_amdgcn_mfma_f32_16x16x32_bf16(a[i], b[j],     \
                                                                        acc[i][j], 0, 0, 0); \
            __builtin_amdgcn_s_setprio(0);                                              \
            __builtin_amdgcn_s_barrier();                                               \
            _Pragma("unroll")                                                           \
            for (int i = 4; i < 8; i++) {                                               \
                const int rowa = wm * 128 + i * 16 + row16;                             \
                a[i] = *(const bf16x8*)(ldsA[buf] + rowa * 32 + ((quad ^ (rowa & 3)) * 8)); \
            }                                                                           \
            __builtin_amdgcn_s_barrier();                                               \
            __builtin_amdgcn_s_setprio(1);                                              \
            _Pragma("unroll")                                                           \
            for (int i = 4; i < 8; i++)                                                 \
                _Pragma("unroll")                                                       \
                for (int j = 0; j < 4; j++)                                             \
                    acc[i][j] = __builtin_amdgcn_mfma_f32_16x16x32_bf16(a[i], b[j],     \
                                                                        acc[i][j], 0, 0, 0); \
            __builtin_amdgcn_s_setprio(0);                                              \
        }

    STAGE(0, 0);
    __syncthreads();        // prologue drain (only time we wait on young loads)
    STAGE(1, 1);            // in flight across tile 0's compute

    // 12 K-tiles, pairwise unrolled for static buffer indices
    #pragma unroll
    for (int tp = 0; tp < 6; tp++) {
        COMPUTE(0);
        __syncthreads();                 // drains stage(2tp+1): issued one full tile ago
        if (tp < 5) STAGE(0, 2 * tp + 2);
        COMPUTE(1);
        __syncthreads();
        if (tp < 5) STAGE(1, 2 * tp + 3);
    }

    #undef STAGE
    #undef COMPUTE

    #pragma unroll
    for (int j = 0; j < 4; j++) {
        const int col = n_base + wn * 64 + j * 16 + row16;
        const float bv = bias[col];
        #pragma unroll
        for (int i = 0; i < 8; i++) {
            const int row0 = m_base + wm * 128 + i * 16 + quad * 4;
            #pragma unroll
            for (int r = 0; r < 4; r++) {
                float v = acc[i][j][r] + bv;
                size_t off = (size_t)(row0 + r) * N + col;
                if (OUT_BF16) ((unsigned short*)Cout)[off] = f2bf(v);
                else          ((float*)Cout)[off]          = v;
            }
        }
    }
}

// ---- MFMA window attention ----
// Block = 256 threads = 4 waves = 4 heads of one window. Wave-private LDS slices,
// no __syncthreads (same-wave DS ops are in-order). Per wave:
//   S^T = mfma_bf16(K-frags, Q-frags): 16 mfma, rows=k (quad*4+r), cols=q (lane&15)
//   softmax over k: 16 in-lane values + shfl_xor(16)/shfl_xor(32) across quads
//   P normalized in-reg, cvt f16, bounced via LDS [q][k] stride PST=68
//   V staged transposed [d][k] f16 stride 68; k=48..63 zero-filled
//   out = mfma_f16(P-frags, V^T-frags): 16 mfma
__global__ __launch_bounds__(256) void attn_mfma(const unsigned short* __restrict__ qkv,
                                                 unsigned short* __restrict__ out) {
    // per-wave slice: P [64][PST] + V^T [32][PST] halves = 96*68*2 B = 13056 B
    __shared__ _Float16 lds[4][96 * PST];

    const int tid  = threadIdx.x;
    const int lane = tid & 63;
    const int wave = tid >> 6;
    const int c    = lane & 15;
    const int quad = lane >> 4;

    const int w  = blockIdx.x / 3;
    const int hg = blockIdx.x % 3;
    const int h  = hg * 4 + wave;

    const int b  = w >> 6;
    const int wi = w & 63;
    const int wy = wi >> 3, wx = wi & 7;
    const int tok0 = b * LTOK + wy * 7 * WW_ + wx * 7;   // token index of t=0

    _Float16* pbuf = lds[wave];
    _Float16* vbuf = lds[wave] + 64 * PST;

    // ---- zero-fill V^T pad columns t in [48,64) ----
    #pragma unroll
    for (int z = 0; z < 8; z++) {
        const int idx = z * 64 + lane;          // 0..511
        const int d   = idx >> 4;               // 0..31
        const int t   = 48 + (idx & 15);        // 48..63
        vbuf[d * PST + t] = (_Float16)0.f;
    }

    // ---- stage V transposed: vbuf[d][t] (overwrites t=48 with real data) ----
    #pragma unroll
    for (int rr = 0; rr < 4; rr++) {
        const int id = rr * 64 + lane;               // 0..195 used (49 tok * 4 chunks)
        if (id < 196) {
            const int t  = id >> 2;
            const int p8 = (id & 3) * 8;
            const int tk = tok0 + (t / 7) * WW_ + (t % 7);
            u16x8 vv = *(const u16x8*)(qkv + (size_t)tk * 1152 + 768 + h * 32 + p8);
            #pragma unroll
            for (int e = 0; e < 8; e++)
                vbuf[(p8 + e) * PST + t] = (_Float16)bf2f(vv[e]);
        }
    }

    // ---- load Q/K fragments (gathered 16B loads, tokens >= 49 clamped) ----
    bf16x8 ak[4], bq[4];
    #pragma unroll
    for (int i = 0; i < 4; i++) {
        int t = i * 16 + c; t = t > 48 ? 48 : t;
        const size_t row = (size_t)(tok0 + (t / 7) * WW_ + (t % 7)) * 1152;
        ak[i] = *(const bf16x8*)(qkv + row + 384 + h * 32 + quad * 8);  // K
        bq[i] = *(const bf16x8*)(qkv + row +       h * 32 + quad * 8);  // Q
    }

    // ---- S^T = K @ Q^T : st[i][j], k = i*16+quad*4+r, q = j*16+c ----
    const f32x4 zero = {0.f, 0.f, 0.f, 0.f};
    f32x4 st[4][4];
    #pragma unroll
    for (int i = 0; i < 4; i++)
        #pragma unroll
        for (int j = 0; j < 4; j++)
            st[i][j] = __builtin_amdgcn_mfma_f32_16x16x32_bf16(ak[i], bq[j], zero, 0, 0, 0);

    // mask k >= 49 (only i==3 tile; k==48 lives at quad==0,r==0)
    #pragma unroll
    for (int j = 0; j < 4; j++) {
        st[3][j][0] = (quad == 0) ? st[3][j][0] : -1e30f;
        st[3][j][1] = -1e30f;
        st[3][j][2] = -1e30f;
        st[3][j][3] = -1e30f;
    }

    // ---- softmax over k per q-column; scale folded into exp arg ----
    const float scale = 0.17677669529663687f;   // 32^-0.5
    #pragma unroll
    for (int j = 0; j < 4; j++) {
        float m = -1e30f;
        #pragma unroll
        for (int i = 0; i < 4; i++)
            #pragma unroll
            for (int r = 0; r < 4; r++) m = fmaxf(m, st[i][j][r]);
        m = fmaxf(m, __shfl_xor(m, 16));
        m = fmaxf(m, __shfl_xor(m, 32));
        const float nm = -m * scale;
        float l = 0.f;
        #pragma unroll
        for (int i = 0; i < 4; i++)
            #pragma unroll
            for (int r = 0; r < 4; r++) {
                float e = __expf(__builtin_fmaf(st[i][j][r], scale, nm));
                st[i][j][r] = e;
                l += e;
            }
        l += __shfl_xor(l, 16);
        l += __shfl_xor(l, 32);
        const float inv = __builtin_amdgcn_rcpf(l);

        // normalized P -> f16 -> LDS [q][k], row stride PST
        const int qrow = j * 16 + c;
        #pragma unroll
        for (int i = 0; i < 4; i++) {
            u16x4 pk;
            #pragma unroll
            for (int r = 0; r < 4; r++) {
                _Float16 hf = (_Float16)(st[i][j][r] * inv);
                unsigned short us; __builtin_memcpy(&us, &hf, 2);
                pk[r] = us;
            }
            *(u16x4*)(pbuf + qrow * PST + i * 16 + quad * 4) = pk;
        }
    }

    // ---- out = P @ V : o[mi][nj], q = mi*16+quad*4+r, d = nj*16+c ----
    f32x4 o[4][2] = {};
    #pragma unroll
    for (int kb = 0; kb < 2; kb++) {
        f16x8 pa[4], vb[2];
        #pragma unroll
        for (int mi = 0; mi < 4; mi++)
            pa[mi] = *(const f16x8*)(pbuf + (mi * 16 + c) * PST + kb * 32 + quad * 8);
        #pragma unroll
        for (int nj = 0; nj < 2; nj++)
            vb[nj] = *(const f16x8*)(vbuf + (nj * 16 + c) * PST + kb * 32 + quad * 8);
        #pragma unroll
        for (int mi = 0; mi < 4; mi++)
            #pragma unroll
            for (int nj = 0; nj < 2; nj++)
                o[mi][nj] = __builtin_amdgcn_mfma_f32_16x16x32_f16(pa[mi], vb[nj], o[mi][nj], 0, 0, 0);
    }

    // ---- store (q < 49 rows only), bf16 ----
    #pragma unroll
    for (int mi = 0; mi < 4; mi++) {
        #pragma unroll
        for (int r = 0; r < 4; r++) {
            const int q = mi * 16 + quad * 4 + r;
            if (q < 49) {
                const size_t trow = (size_t)(tok0 + (q / 7) * WW_ + (q % 7)) * DIM + h * 32;
                #pragma unroll
                for (int nj = 0; nj < 2; nj++)
                    out[trow + nj * 16 + c] = f2bf(o[mi][nj][r]);
            }
        }
    }
}

extern "C" void kernel_launch(void* const* d_in, const int* in_sizes, int n_in,
                              void* d_out, int out_size, void* d_ws, size_t ws_size,
                              hipStream_t stream) {
    const float* x      = (const float*)d_in[0];
    const float* qkv_w  = (const float*)d_in[1];
    const float* qkv_b  = (const float*)d_in[2];
    const float* proj_w = (const float*)d_in[3];
    const float* proj_b = (const float*)d_in[4];
    float* out = (float*)d_out;

    char* ws = (char*)d_ws;
    unsigned short* qkv_bf = (unsigned short*)ws;
    unsigned short* xa_bf  = (unsigned short*)(ws + (size_t)MTOK * 1152 * 2);
    unsigned short* qw_bf  = (unsigned short*)(ws + (size_t)MTOK * 1152 * 2 + (size_t)MTOK * DIM * 2);
    unsigned short* pw_bf  = qw_bf + 3 * DIM * DIM;

    const int n4 = MTOK * DIM / 4;
    cvt_x_kernel<<<(n4 + 255) / 256, 256, 0, stream>>>(x, xa_bf, n4);
    cvt_w_kernel<<<(4 * DIM * DIM + 255) / 256, 256, 0, stream>>>(qkv_w, proj_w, qw_bf, pw_bf);

    // QKV: grid (196 m-tiles of 512) x (9 n-tiles of 128)
    gemm_bt<true><<<196 * 9, 512, 0, stream>>>(xa_bf, qw_bf, qkv_b, qkv_bf, 3 * DIM, 9);

    // attention: one block per (window, head-group of 4), 4 waves = 4 heads
    attn_mfma<<<2048 * 3, 256, 0, stream>>>(qkv_bf, xa_bf);

    // proj: grid (196 m-tiles) x (3 n-tiles)
    gemm_bt<false><<<196 * 3, 512, 0, stream>>>(xa_bf, pw_bf, proj_b, out, DIM, 3);
}

// Round 7
// 620.278 us; speedup vs baseline: 1.0073x; 1.0073x over previous
//
#include <hip/hip_runtime.h>
#include <hip/hip_bf16.h>

#define DIM   384
#define NH    12
#define HD    32
#define BATCH 32
#define HH    56
#define WW_   56
#define LTOK  3136
#define MTOK  100352
#define KDIM  384

// LDS row stride (halves) for P and V^T buffers: >=64 extent, bank-even b128
#define PST   68

typedef __attribute__((ext_vector_type(8))) short          bf16x8;
typedef __attribute__((ext_vector_type(8))) _Float16       f16x8;
typedef __attribute__((ext_vector_type(8))) unsigned short u16x8;
typedef __attribute__((ext_vector_type(4))) float          f32x4;
typedef __attribute__((ext_vector_type(4))) unsigned short u16x4;

static __device__ __forceinline__ unsigned short f2bf(float f) {
    __hip_bfloat16 h = __float2bfloat16(f);
    unsigned short u; __builtin_memcpy(&u, &h, 2); return u;
}
static __device__ __forceinline__ float bf2f(unsigned short s) {
    unsigned int u = ((unsigned int)s) << 16;
    float f; __builtin_memcpy(&f, &u, 4); return f;
}

static __device__ __forceinline__ void async_cp16(const unsigned short* g, unsigned short* l) {
    __builtin_amdgcn_global_load_lds((const __attribute__((address_space(1))) void*)g,
                                     (__attribute__((address_space(3))) void*)l, 16, 0, 0);
}

// ---- fp32 -> bf16 bulk convert (x) ----
__global__ __launch_bounds__(256) void cvt_x_kernel(const float* __restrict__ in,
                                                    unsigned short* __restrict__ out, int n4) {
    int i = blockIdx.x * 256 + threadIdx.x;
    if (i >= n4) return;
    f32x4 v = *(const f32x4*)(in + 4 * (size_t)i);
    u16x4 u;
    u[0] = f2bf(v[0]); u[1] = f2bf(v[1]); u[2] = f2bf(v[2]); u[3] = f2bf(v[3]);
    *(u16x4*)(out + 4 * (size_t)i) = u;
}

__global__ __launch_bounds__(256) void cvt_w_kernel(const float* __restrict__ qw,
                                                    const float* __restrict__ pw,
                                                    unsigned short* __restrict__ qwb,
                                                    unsigned short* __restrict__ pwb) {
    int i = blockIdx.x * 256 + threadIdx.x;
    if (i < 3 * DIM * DIM) {
        qwb[i] = f2bf(qw[i]);
    } else {
        int j = i - 3 * DIM * DIM;
        if (j < DIM * DIM) pwb[j] = f2bf(pw[j]);
    }
}

// ---- LDS-staged GEMM: C[M,N] = A[M,384] @ W[N,384]^T + bias ----
// BM=512, BN=128, BK=32, 512 threads = 8 waves (4m x 2n), wave-tile 128x64.
// Double-buffered LDS (80 KB), stage-ahead-1; per K-tile two MFMA clusters of 16
// wrapped in raw s_barrier + setprio (scheduling only; intra-tile LDS is read-only).
// Chunk-slot permutation: pos = kc ^ ((row>>1)&3). With 16-dword rows this makes
// each 16-lane quarter-wave of a ds_read_b128 cover all 8 bank-group residues
// exactly twice (2-way = free), unlike kc^(row&3) which was 4-way (8.1M conflicts
// measured in round 5). Bijective XCD swizzle (m204) since grid % 8 != 0.
template<bool OUT_BF16>
__global__ __launch_bounds__(512, 2) void gemm_bt(const unsigned short* __restrict__ A,
                                                  const unsigned short* __restrict__ W,
                                                  const float* __restrict__ bias,
                                                  void* __restrict__ Cout,
                                                  int N, int nbn) {
    __shared__ unsigned short ldsA[2][512 * 32];   // 32 KB per buffer
    __shared__ unsigned short ldsB[2][128 * 32];   // 8 KB per buffer

    const int tid   = threadIdx.x;
    const int lane  = tid & 63;
    const int wave  = tid >> 6;          // 0..7
    const int wm    = wave >> 1;         // 0..3 -> m offset wm*128
    const int wn    = wave & 1;          // 0..1 -> n offset wn*64
    const int row16 = lane & 15, quad = lane >> 4;

    // bijective XCD-chunked swizzle (works for any gridDim.x)
    const int nwg = gridDim.x;
    const int qq  = nwg >> 3, rr = nwg & 7;
    const int xcd = blockIdx.x & 7, bidx = blockIdx.x >> 3;
    const int wg  = (xcd < rr ? xcd * (qq + 1) : rr * (qq + 1) + (xcd - rr) * qq) + bidx;

    const int mt = wg / nbn, nt = wg % nbn;
    const int m_base = mt * 512, n_base = nt * 128;

    const unsigned short* Abase = A + (size_t)m_base * KDIM;
    const unsigned short* Wbase = W + (size_t)n_base * KDIM;

    // staging maps: rows have 4 16B-chunks (BK=32); slot pos p holds global
    // chunk kc = p ^ ((row>>1)&3)  (quarter-wave bank-even permutation)
    int sArow[4], sAkc[4];
    #pragma unroll
    for (int i = 0; i < 4; i++) {
        int c = i * 512 + tid;           // A chunk 0..2047
        sArow[i] = c >> 2;
        sAkc[i]  = (c & 3) ^ ((sArow[i] >> 1) & 3);
    }
    const int sBrow = tid >> 2;          // B chunk = tid (0..511)
    const int sBkc  = (tid & 3) ^ ((sBrow >> 1) & 3);

    f32x4 acc[8][4] = {};

    #define STAGE(buf, kt)                                                              \
        {                                                                               \
            const int k0 = (kt) * 32;                                                   \
            _Pragma("unroll")                                                           \
            for (int i = 0; i < 4; i++)                                                 \
                async_cp16(Abase + (size_t)sArow[i] * KDIM + k0 + sAkc[i] * 8,          \
                           ldsA[buf] + (i * 512 + wave * 64) * 8);                      \
            async_cp16(Wbase + (size_t)sBrow * KDIM + k0 + sBkc * 8,                    \
                       ldsB[buf] + (wave * 64) * 8);                                    \
        }

    #define COMPUTE(buf)                                                                \
        {                                                                               \
            bf16x8 a[8], b[4];                                                          \
            _Pragma("unroll")                                                           \
            for (int i = 0; i < 4; i++) {                                               \
                const int rowa = wm * 128 + i * 16 + row16;                             \
                a[i] = *(const bf16x8*)(ldsA[buf] + rowa * 32 + ((quad ^ ((rowa >> 1) & 3)) * 8)); \
            }                                                                           \
            _Pragma("unroll")                                                           \
            for (int j = 0; j < 4; j++) {                                               \
                const int rowb = wn * 64 + j * 16 + row16;                              \
                b[j] = *(const bf16x8*)(ldsB[buf] + rowb * 32 + ((quad ^ ((rowb >> 1) & 3)) * 8)); \
            }                                                                           \
            __builtin_amdgcn_s_barrier();                                               \
            __builtin_amdgcn_s_setprio(1);                                              \
            _Pragma("unroll")                                                           \
            for (int i = 0; i < 4; i++)                                                 \
                _Pragma("unroll")                                                       \
                for (int j = 0; j < 4; j++)                                             \
                    acc[i][j] = __builtin_amdgcn_mfma_f32_16x16x32_bf16(a[i], b[j],     \
                                                                        acc[i][j], 0, 0, 0); \
            __builtin_amdgcn_s_setprio(0);                                              \
            __builtin_amdgcn_s_barrier();                                               \
            _Pragma("unroll")                                                           \
            for (int i = 4; i < 8; i++) {                                               \
                const int rowa = wm * 128 + i * 16 + row16;                             \
                a[i] = *(const bf16x8*)(ldsA[buf] + rowa * 32 + ((quad ^ ((rowa >> 1) & 3)) * 8)); \
            }                                                                           \
            __builtin_amdgcn_s_barrier();                                               \
            __builtin_amdgcn_s_setprio(1);                                              \
            _Pragma("unroll")                                                           \
            for (int i = 4; i < 8; i++)                                                 \
                _Pragma("unroll")                                                       \
                for (int j = 0; j < 4; j++)                                             \
                    acc[i][j] = __builtin_amdgcn_mfma_f32_16x16x32_bf16(a[i], b[j],     \
                                                                        acc[i][j], 0, 0, 0); \
            __builtin_amdgcn_s_setprio(0);                                              \
        }

    STAGE(0, 0);
    __syncthreads();        // prologue drain (only time we wait on young loads)
    STAGE(1, 1);            // in flight across tile 0's compute

    // 12 K-tiles, pairwise unrolled for static buffer indices
    #pragma unroll
    for (int tp = 0; tp < 6; tp++) {
        COMPUTE(0);
        __syncthreads();                 // drains stage issued one full compute ago
        if (tp < 5) STAGE(0, 2 * tp + 2);
        COMPUTE(1);
        __syncthreads();
        if (tp < 5) STAGE(1, 2 * tp + 3);
    }

    #undef STAGE
    #undef COMPUTE

    #pragma unroll
    for (int j = 0; j < 4; j++) {
        const int col = n_base + wn * 64 + j * 16 + row16;
        const float bv = bias[col];
        #pragma unroll
        for (int i = 0; i < 8; i++) {
            const int row0 = m_base + wm * 128 + i * 16 + quad * 4;
            #pragma unroll
            for (int r = 0; r < 4; r++) {
                float v = acc[i][j][r] + bv;
                size_t off = (size_t)(row0 + r) * N + col;
                if (OUT_BF16) ((unsigned short*)Cout)[off] = f2bf(v);
                else          ((float*)Cout)[off]          = v;
            }
        }
    }
}

// ---- MFMA window attention ----
// Block = 256 threads = 4 waves = 4 heads of one window. Wave-private LDS slices,
// no __syncthreads (same-wave DS ops are in-order). Per wave:
//   S^T = mfma_bf16(K-frags, Q-frags): 16 mfma, rows=k (quad*4+r), cols=q (lane&15)
//   softmax over k: 16 in-lane values + shfl_xor(16)/shfl_xor(32) across quads
//   P normalized in-reg, cvt f16, bounced via LDS [q][k] stride PST=68
//   V staged transposed [d][k] f16 stride 68; k=48..63 zero-filled
//   out = mfma_f16(P-frags, V^T-frags): 16 mfma
__global__ __launch_bounds__(256) void attn_mfma(const unsigned short* __restrict__ qkv,
                                                 unsigned short* __restrict__ out) {
    // per-wave slice: P [64][PST] + V^T [32][PST] halves = 96*68*2 B = 13056 B
    __shared__ _Float16 lds[4][96 * PST];

    const int tid  = threadIdx.x;
    const int lane = tid & 63;
    const int wave = tid >> 6;
    const int c    = lane & 15;
    const int quad = lane >> 4;

    const int w  = blockIdx.x / 3;
    const int hg = blockIdx.x % 3;
    const int h  = hg * 4 + wave;

    const int b  = w >> 6;
    const int wi = w & 63;
    const int wy = wi >> 3, wx = wi & 7;
    const int tok0 = b * LTOK + wy * 7 * WW_ + wx * 7;   // token index of t=0

    _Float16* pbuf = lds[wave];
    _Float16* vbuf = lds[wave] + 64 * PST;

    // ---- zero-fill V^T pad columns t in [48,64) ----
    #pragma unroll
    for (int z = 0; z < 8; z++) {
        const int idx = z * 64 + lane;          // 0..511
        const int d   = idx >> 4;               // 0..31
        const int t   = 48 + (idx & 15);        // 48..63
        vbuf[d * PST + t] = (_Float16)0.f;
    }

    // ---- stage V transposed: vbuf[d][t] (overwrites t=48 with real data) ----
    #pragma unroll
    for (int rr = 0; rr < 4; rr++) {
        const int id = rr * 64 + lane;               // 0..195 used (49 tok * 4 chunks)
        if (id < 196) {
            const int t  = id >> 2;
            const int p8 = (id & 3) * 8;
            const int tk = tok0 + (t / 7) * WW_ + (t % 7);
            u16x8 vv = *(const u16x8*)(qkv + (size_t)tk * 1152 + 768 + h * 32 + p8);
            #pragma unroll
            for (int e = 0; e < 8; e++)
                vbuf[(p8 + e) * PST + t] = (_Float16)bf2f(vv[e]);
        }
    }

    // ---- load Q/K fragments (gathered 16B loads, tokens >= 49 clamped) ----
    bf16x8 ak[4], bq[4];
    #pragma unroll
    for (int i = 0; i < 4; i++) {
        int t = i * 16 + c; t = t > 48 ? 48 : t;
        const size_t row = (size_t)(tok0 + (t / 7) * WW_ + (t % 7)) * 1152;
        ak[i] = *(const bf16x8*)(qkv + row + 384 + h * 32 + quad * 8);  // K
        bq[i] = *(const bf16x8*)(qkv + row +       h * 32 + quad * 8);  // Q
    }

    // ---- S^T = K @ Q^T : st[i][j], k = i*16+quad*4+r, q = j*16+c ----
    const f32x4 zero = {0.f, 0.f, 0.f, 0.f};
    f32x4 st[4][4];
    #pragma unroll
    for (int i = 0; i < 4; i++)
        #pragma unroll
        for (int j = 0; j < 4; j++)
            st[i][j] = __builtin_amdgcn_mfma_f32_16x16x32_bf16(ak[i], bq[j], zero, 0, 0, 0);

    // mask k >= 49 (only i==3 tile; k==48 lives at quad==0,r==0)
    #pragma unroll
    for (int j = 0; j < 4; j++) {
        st[3][j][0] = (quad == 0) ? st[3][j][0] : -1e30f;
        st[3][j][1] = -1e30f;
        st[3][j][2] = -1e30f;
        st[3][j][3] = -1e30f;
    }

    // ---- softmax over k per q-column; scale folded into exp arg ----
    const float scale = 0.17677669529663687f;   // 32^-0.5
    #pragma unroll
    for (int j = 0; j < 4; j++) {
        float m = -1e30f;
        #pragma unroll
        for (int i = 0; i < 4; i++)
            #pragma unroll
            for (int r = 0; r < 4; r++) m = fmaxf(m, st[i][j][r]);
        m = fmaxf(m, __shfl_xor(m, 16));
        m = fmaxf(m, __shfl_xor(m, 32));
        const float nm = -m * scale;
        float l = 0.f;
        #pragma unroll
        for (int i = 0; i < 4; i++)
            #pragma unroll
            for (int r = 0; r < 4; r++) {
                float e = __expf(__builtin_fmaf(st[i][j][r], scale, nm));
                st[i][j][r] = e;
                l += e;
            }
        l += __shfl_xor(l, 16);
        l += __shfl_xor(l, 32);
        const float inv = __builtin_amdgcn_rcpf(l);

        // normalized P -> f16 -> LDS [q][k], row stride PST
        const int qrow = j * 16 + c;
        #pragma unroll
        for (int i = 0; i < 4; i++) {
            u16x4 pk;
            #pragma unroll
            for (int r = 0; r < 4; r++) {
                _Float16 hf = (_Float16)(st[i][j][r] * inv);
                unsigned short us; __builtin_memcpy(&us, &hf, 2);
                pk[r] = us;
            }
            *(u16x4*)(pbuf + qrow * PST + i * 16 + quad * 4) = pk;
        }
    }

    // ---- out = P @ V : o[mi][nj], q = mi*16+quad*4+r, d = nj*16+c ----
    f32x4 o[4][2] = {};
    #pragma unroll
    for (int kb = 0; kb < 2; kb++) {
        f16x8 pa[4], vb[2];
        #pragma unroll
        for (int mi = 0; mi < 4; mi++)
            pa[mi] = *(const f16x8*)(pbuf + (mi * 16 + c) * PST + kb * 32 + quad * 8);
        #pragma unroll
        for (int nj = 0; nj < 2; nj++)
            vb[nj] = *(const f16x8*)(vbuf + (nj * 16 + c) * PST + kb * 32 + quad * 8);
        #pragma unroll
        for (int mi = 0; mi < 4; mi++)
            #pragma unroll
            for (int nj = 0; nj < 2; nj++)
                o[mi][nj] = __builtin_amdgcn_mfma_f32_16x16x32_f16(pa[mi], vb[nj], o[mi][nj], 0, 0, 0);
    }

    // ---- store (q < 49 rows only), bf16 ----
    #pragma unroll
    for (int mi = 0; mi < 4; mi++) {
        #pragma unroll
        for (int r = 0; r < 4; r++) {
            const int q = mi * 16 + quad * 4 + r;
            if (q < 49) {
                const size_t trow = (size_t)(tok0 + (q / 7) * WW_ + (q % 7)) * DIM + h * 32;
                #pragma unroll
                for (int nj = 0; nj < 2; nj++)
                    out[trow + nj * 16 + c] = f2bf(o[mi][nj][r]);
            }
        }
    }
}

extern "C" void kernel_launch(void* const* d_in, const int* in_sizes, int n_in,
                              void* d_out, int out_size, void* d_ws, size_t ws_size,
                              hipStream_t stream) {
    const float* x      = (const float*)d_in[0];
    const float* qkv_w  = (const float*)d_in[1];
    const float* qkv_b  = (const float*)d_in[2];
    const float* proj_w = (const float*)d_in[3];
    const float* proj_b = (const float*)d_in[4];
    float* out = (float*)d_out;

    char* ws = (char*)d_ws;
    unsigned short* qkv_bf = (unsigned short*)ws;
    unsigned short* xa_bf  = (unsigned short*)(ws + (size_t)MTOK * 1152 * 2);
    unsigned short* qw_bf  = (unsigned short*)(ws + (size_t)MTOK * 1152 * 2 + (size_t)MTOK * DIM * 2);
    unsigned short* pw_bf  = qw_bf + 3 * DIM * DIM;

    const int n4 = MTOK * DIM / 4;
    cvt_x_kernel<<<(n4 + 255) / 256, 256, 0, stream>>>(x, xa_bf, n4);
    cvt_w_kernel<<<(4 * DIM * DIM + 255) / 256, 256, 0, stream>>>(qkv_w, proj_w, qw_bf, pw_bf);

    // QKV: grid (196 m-tiles of 512) x (9 n-tiles of 128)
    gemm_bt<true><<<196 * 9, 512, 0, stream>>>(xa_bf, qw_bf, qkv_b, qkv_bf, 3 * DIM, 9);

    // attention: one block per (window, head-group of 4), 4 waves = 4 heads
    attn_mfma<<<2048 * 3, 256, 0, stream>>>(qkv_bf, xa_bf);

    // proj: grid (196 m-tiles) x (3 n-tiles)
    gemm_bt<false><<<196 * 3, 512, 0, stream>>>(xa_bf, pw_bf, proj_b, out, DIM, 3);
}

// Round 9
// 557.388 us; speedup vs baseline: 1.1209x; 1.1128x over previous
//
#include <hip/hip_runtime.h>
#include <hip/hip_bf16.h>

#define DIM   384
#define NH    12
#define HD    32
#define BATCH 32
#define HH    56
#define WW_   56
#define LTOK  3136
#define MTOK  100352
#define KDIM  384
#define BK    64

// LDS row stride (halves) for P and V^T buffers: >=64 extent, bank-even b128
#define PST   68

typedef __attribute__((ext_vector_type(8))) short          bf16x8;
typedef __attribute__((ext_vector_type(8))) _Float16       f16x8;
typedef __attribute__((ext_vector_type(8))) unsigned short u16x8;
typedef __attribute__((ext_vector_type(4))) float          f32x4;
typedef __attribute__((ext_vector_type(4))) unsigned short u16x4;

static __device__ __forceinline__ unsigned short f2bf(float f) {
    __hip_bfloat16 h = __float2bfloat16(f);
    unsigned short u; __builtin_memcpy(&u, &h, 2); return u;
}
static __device__ __forceinline__ float bf2f(unsigned short s) {
    unsigned int u = ((unsigned int)s) << 16;
    float f; __builtin_memcpy(&f, &u, 4); return f;
}

static __device__ __forceinline__ void async_cp16(const unsigned short* g, unsigned short* l) {
    __builtin_amdgcn_global_load_lds((const __attribute__((address_space(1))) void*)g,
                                     (__attribute__((address_space(3))) void*)l, 16, 0, 0);
}

__global__ __launch_bounds__(256) void cvt_w_kernel(const float* __restrict__ qw,
                                                    const float* __restrict__ pw,
                                                    unsigned short* __restrict__ qwb,
                                                    unsigned short* __restrict__ pwb) {
    int i = blockIdx.x * 256 + threadIdx.x;
    if (i < 3 * DIM * DIM) {
        qwb[i] = f2bf(qw[i]);
    } else {
        int j = i - 3 * DIM * DIM;
        if (j < DIM * DIM) pwb[j] = f2bf(pw[j]);
    }
}

// ---- LDS-staged GEMM: C[M,N] = A[M,384] @ W[N,384]^T + bias ----
// Round-3 structure (proven best): 128x128 C-tile, 4 waves 2x2, BK=64,
// double-buffered LDS (64 KB), stage-ahead-1, XCD-chunked swizzle (grid%8==0).
// AF32 path (QKV): A is f32 in HBM; fused cvt — reg-stage A (issue 8 dwordx4
// early, cvt+ds_write after COMPUTE). Removes the standalone cvt_x pass.
// Write slot permutation pos^(row&7) == read side; 2-way per quarter-wave (free).
// !AF32 path (proj): byte-identical round-3 global_load_lds staging.
template<bool AF32, bool OUT_BF16>
__global__ __launch_bounds__(256) void gemm_bt(const void* __restrict__ Ain,
                                               const unsigned short* __restrict__ W,
                                               const float* __restrict__ bias,
                                               void* __restrict__ Cout,
                                               int N, int nbn) {
    __shared__ unsigned short ldsA[2][128 * BK];
    __shared__ unsigned short ldsB[2][128 * BK];

    const int tid   = threadIdx.x;
    const int lane  = tid & 63;
    const int wave  = tid >> 6;
    const int wm    = wave >> 1, wn = wave & 1;
    const int row16 = lane & 15, quad = lane >> 4;

    // XCD-chunked swizzle: grid % 8 == 0 for both instances (7056 / 2352)
    const int cpx = gridDim.x >> 3;
    const int wg  = (blockIdx.x & 7) * cpx + (blockIdx.x >> 3);
    const int mt = wg / nbn;
    const int nt = wg % nbn;
    const int m_base = mt * 128;
    const int n_base = nt * 128;

    const unsigned short* Abf = (const unsigned short*)Ain + (size_t)m_base * KDIM;
    const float*          Af  = (const float*)Ain          + (size_t)m_base * KDIM;
    const unsigned short* Wbase = W + (size_t)n_base * KDIM;

    // staging coordinates: chunk c = i*256+tid, row = c>>3, pos = c&7
    int srow[4], spos[4], sxor[4];
    #pragma unroll
    for (int i = 0; i < 4; i++) {
        int c = i * 256 + tid;
        srow[i] = c >> 3;
        spos[i] = c & 7;
        sxor[i] = spos[i] ^ (srow[i] & 7);
    }

    f32x4 ar[4][2];          // AF32: in-flight A registers (one K-step tile)
    f32x4 acc[4][4] = {};

    // -- A staging, global_load_lds path (proj): source pre-swizzled, dest linear
    #define STAGE_A(buf, kt)                                                            \
        {                                                                               \
            const int k0 = (kt) * BK;                                                   \
            _Pragma("unroll")                                                           \
            for (int i = 0; i < 4; i++)                                                 \
                async_cp16(Abf + (size_t)srow[i] * KDIM + k0 + sxor[i] * 8,             \
                           ldsA[buf] + (i * 256 + wave * 64) * 8);                      \
        }

    // -- A staging, fused-cvt path (QKV): straight f32 loads into regs
    #define LOADA(kt)                                                                   \
        {                                                                               \
            const int k0 = (kt) * BK;                                                   \
            _Pragma("unroll")                                                           \
            for (int i = 0; i < 4; i++) {                                               \
                const float* s = Af + (size_t)srow[i] * KDIM + k0 + spos[i] * 8;        \
                ar[i][0] = *(const f32x4*)s;                                            \
                ar[i][1] = *(const f32x4*)(s + 4);                                      \
            }                                                                           \
        }

    // cvt + ds_write to the XOR'd slot (matches read side; 2-way = free)
    #define CVTW(buf)                                                                   \
        {                                                                               \
            _Pragma("unroll")                                                           \
            for (int i = 0; i < 4; i++) {                                               \
                u16x8 u;                                                                \
                _Pragma("unroll")                                                       \
                for (int e = 0; e < 4; e++) {                                           \
                    u[e]     = f2bf(ar[i][0][e]);                                       \
                    u[e + 4] = f2bf(ar[i][1][e]);                                       \
                }                                                                       \
                *(u16x8*)(ldsA[buf] + srow[i] * BK + sxor[i] * 8) = u;                  \
            }                                                                           \
        }

    #define STAGE_W(buf, kt)                                                            \
        {                                                                               \
            const int k0 = (kt) * BK;                                                   \
            _Pragma("unroll")                                                           \
            for (int i = 0; i < 4; i++)                                                 \
                async_cp16(Wbase + (size_t)srow[i] * KDIM + k0 + sxor[i] * 8,           \
                           ldsB[buf] + (i * 256 + wave * 64) * 8);                      \
        }

    #define COMPUTE(buf)                                                                \
        {                                                                               \
            _Pragma("unroll")                                                           \
            for (int ks = 0; ks < 2; ks++) {                                            \
                const int kc = ks * 4 + quad;                                           \
                bf16x8 a[4], b[4];                                                      \
                _Pragma("unroll")                                                       \
                for (int i = 0; i < 4; i++) {                                           \
                    const int row = wm * 64 + i * 16 + row16;                           \
                    a[i] = *(const bf16x8*)(ldsA[buf] + row * BK + ((kc ^ (row & 7)) * 8)); \
                }                                                                       \
                _Pragma("unroll")                                                       \
                for (int j = 0; j < 4; j++) {                                           \
                    const int row = wn * 64 + j * 16 + row16;                           \
                    b[j] = *(const bf16x8*)(ldsB[buf] + row * BK + ((kc ^ (row & 7)) * 8)); \
                }                                                                       \
                _Pragma("unroll")                                                       \
                for (int i = 0; i < 4; i++) {                                           \
                    _Pragma("unroll")                                                   \
                    for (int j = 0; j < 4; j++)                                         \
                        acc[i][j] = __builtin_amdgcn_mfma_f32_16x16x32_bf16(a[i], b[j], \
                                                                            acc[i][j], 0, 0, 0); \
                }                                                                       \
            }                                                                           \
        }

    // ---- prologue: tile 0 into buf0 ----
    if constexpr (AF32) { LOADA(0); CVTW(0); }   // cvt waits its own loads (one-time)
    else                { STAGE_A(0, 0); }
    STAGE_W(0, 0);
    __syncthreads();

    // ---- 6 K-steps, pairwise unrolled; stage-ahead-1 on the other buffer ----
    #pragma unroll
    for (int tp = 0; tp < 3; tp++) {
        if constexpr (AF32) { LOADA(2 * tp + 1); }   // issue early, land under COMPUTE
        else                { STAGE_A(1, 2 * tp + 1); }
        STAGE_W(1, 2 * tp + 1);
        COMPUTE(0);
        if constexpr (AF32) { CVTW(1); }             // write late (buf1 free since last sync)
        __syncthreads();
        if (tp < 2) {
            if constexpr (AF32) { LOADA(2 * tp + 2); }
            else                { STAGE_A(0, 2 * tp + 2); }
            STAGE_W(0, 2 * tp + 2);
        }
        COMPUTE(1);
        if constexpr (AF32) { if (tp < 2) { CVTW(0); } }
        __syncthreads();
    }

    #undef STAGE_A
    #undef LOADA
    #undef CVTW
    #undef STAGE_W
    #undef COMPUTE

    #pragma unroll
    for (int j = 0; j < 4; j++) {
        const int col = n_base + wn * 64 + j * 16 + row16;
        const float bv = bias[col];
        #pragma unroll
        for (int i = 0; i < 4; i++) {
            const int row0 = m_base + wm * 64 + i * 16 + quad * 4;
            #pragma unroll
            for (int r = 0; r < 4; r++) {
                float v = acc[i][j][r] + bv;
                size_t off = (size_t)(row0 + r) * N + col;
                if (OUT_BF16) ((unsigned short*)Cout)[off] = f2bf(v);
                else          ((float*)Cout)[off]          = v;
            }
        }
    }
}

// ---- MFMA window attention ----
// Block = 256 threads = 4 waves = 4 heads of one window. Wave-private LDS slices,
// no __syncthreads (same-wave DS ops are in-order). Per wave:
//   S^T = mfma_bf16(K-frags, Q-frags): 16 mfma, rows=k (quad*4+r), cols=q (lane&15)
//   softmax over k: 16 in-lane values + shfl_xor(16)/shfl_xor(32) across quads
//   P normalized in-reg, cvt f16, bounced via LDS [q][k] stride PST=68
//   V staged transposed [d][k] f16 stride 68; k=48..63 zero-filled
//   out = mfma_f16(P-frags, V^T-frags): 16 mfma
__global__ __launch_bounds__(256) void attn_mfma(const unsigned short* __restrict__ qkv,
                                                 unsigned short* __restrict__ out) {
    // per-wave slice: P [64][PST] + V^T [32][PST] halves = 96*68*2 B = 13056 B
    __shared__ _Float16 lds[4][96 * PST];

    const int tid  = threadIdx.x;
    const int lane = tid & 63;
    const int wave = tid >> 6;
    const int c    = lane & 15;
    const int quad = lane >> 4;

    const int w  = blockIdx.x / 3;
    const int hg = blockIdx.x % 3;
    const int h  = hg * 4 + wave;

    const int b  = w >> 6;
    const int wi = w & 63;
    const int wy = wi >> 3, wx = wi & 7;
    const int tok0 = b * LTOK + wy * 7 * WW_ + wx * 7;   // token index of t=0

    _Float16* pbuf = lds[wave];
    _Float16* vbuf = lds[wave] + 64 * PST;

    // ---- zero-fill V^T pad columns t in [48,64) ----
    #pragma unroll
    for (int z = 0; z < 8; z++) {
        const int idx = z * 64 + lane;          // 0..511
        const int d   = idx >> 4;               // 0..31
        const int t   = 48 + (idx & 15);        // 48..63
        vbuf[d * PST + t] = (_Float16)0.f;
    }

    // ---- stage V transposed: vbuf[d][t] (overwrites t=48 with real data) ----
    #pragma unroll
    for (int rr = 0; rr < 4; rr++) {
        const int id = rr * 64 + lane;               // 0..195 used (49 tok * 4 chunks)
        if (id < 196) {
            const int t  = id >> 2;
            const int p8 = (id & 3) * 8;
            const int tk = tok0 + (t / 7) * WW_ + (t % 7);
            u16x8 vv = *(const u16x8*)(qkv + (size_t)tk * 1152 + 768 + h * 32 + p8);
            #pragma unroll
            for (int e = 0; e < 8; e++)
                vbuf[(p8 + e) * PST + t] = (_Float16)bf2f(vv[e]);
        }
    }

    // ---- load Q/K fragments (gathered 16B loads, tokens >= 49 clamped) ----
    bf16x8 ak[4], bq[4];
    #pragma unroll
    for (int i = 0; i < 4; i++) {
        int t = i * 16 + c; t = t > 48 ? 48 : t;
        const size_t row = (size_t)(tok0 + (t / 7) * WW_ + (t % 7)) * 1152;
        ak[i] = *(const bf16x8*)(qkv + row + 384 + h * 32 + quad * 8);  // K
        bq[i] = *(const bf16x8*)(qkv + row +       h * 32 + quad * 8);  // Q
    }

    // ---- S^T = K @ Q^T : st[i][j], k = i*16+quad*4+r, q = j*16+c ----
    const f32x4 zero = {0.f, 0.f, 0.f, 0.f};
    f32x4 st[4][4];
    #pragma unroll
    for (int i = 0; i < 4; i++)
        #pragma unroll
        for (int j = 0; j < 4; j++)
            st[i][j] = __builtin_amdgcn_mfma_f32_16x16x32_bf16(ak[i], bq[j], zero, 0, 0, 0);

    // mask k >= 49 (only i==3 tile; k==48 lives at quad==0,r==0)
    #pragma unroll
    for (int j = 0; j < 4; j++) {
        st[3][j][0] = (quad == 0) ? st[3][j][0] : -1e30f;
        st[3][j][1] = -1e30f;
        st[3][j][2] = -1e30f;
        st[3][j][3] = -1e30f;
    }

    // ---- softmax over k per q-column; scale folded into exp arg ----
    const float scale = 0.17677669529663687f;   // 32^-0.5
    #pragma unroll
    for (int j = 0; j < 4; j++) {
        float m = -1e30f;
        #pragma unroll
        for (int i = 0; i < 4; i++)
            #pragma unroll
            for (int r = 0; r < 4; r++) m = fmaxf(m, st[i][j][r]);
        m = fmaxf(m, __shfl_xor(m, 16));
        m = fmaxf(m, __shfl_xor(m, 32));
        const float nm = -m * scale;
        float l = 0.f;
        #pragma unroll
        for (int i = 0; i < 4; i++)
            #pragma unroll
            for (int r = 0; r < 4; r++) {
                float e = __expf(__builtin_fmaf(st[i][j][r], scale, nm));
                st[i][j][r] = e;
                l += e;
            }
        l += __shfl_xor(l, 16);
        l += __shfl_xor(l, 32);
        const float inv = __builtin_amdgcn_rcpf(l);

        // normalized P -> f16 -> LDS [q][k], row stride PST
        const int qrow = j * 16 + c;
        #pragma unroll
        for (int i = 0; i < 4; i++) {
            u16x4 pk;
            #pragma unroll
            for (int r = 0; r < 4; r++) {
                _Float16 hf = (_Float16)(st[i][j][r] * inv);
                unsigned short us; __builtin_memcpy(&us, &hf, 2);
                pk[r] = us;
            }
            *(u16x4*)(pbuf + qrow * PST + i * 16 + quad * 4) = pk;
        }
    }

    // ---- out = P @ V : o[mi][nj], q = mi*16+quad*4+r, d = nj*16+c ----
    f32x4 o[4][2] = {};
    #pragma unroll
    for (int kb = 0; kb < 2; kb++) {
        f16x8 pa[4], vb[2];
        #pragma unroll
        for (int mi = 0; mi < 4; mi++)
            pa[mi] = *(const f16x8*)(pbuf + (mi * 16 + c) * PST + kb * 32 + quad * 8);
        #pragma unroll
        for (int nj = 0; nj < 2; nj++)
            vb[nj] = *(const f16x8*)(vbuf + (nj * 16 + c) * PST + kb * 32 + quad * 8);
        #pragma unroll
        for (int mi = 0; mi < 4; mi++)
            #pragma unroll
            for (int nj = 0; nj < 2; nj++)
                o[mi][nj] = __builtin_amdgcn_mfma_f32_16x16x32_f16(pa[mi], vb[nj], o[mi][nj], 0, 0, 0);
    }

    // ---- store (q < 49 rows only), bf16 ----
    #pragma unroll
    for (int mi = 0; mi < 4; mi++) {
        #pragma unroll
        for (int r = 0; r < 4; r++) {
            const int q = mi * 16 + quad * 4 + r;
            if (q < 49) {
                const size_t trow = (size_t)(tok0 + (q / 7) * WW_ + (q % 7)) * DIM + h * 32;
                #pragma unroll
                for (int nj = 0; nj < 2; nj++)
                    out[trow + nj * 16 + c] = f2bf(o[mi][nj][r]);
            }
        }
    }
}

extern "C" void kernel_launch(void* const* d_in, const int* in_sizes, int n_in,
                              void* d_out, int out_size, void* d_ws, size_t ws_size,
                              hipStream_t stream) {
    const float* x      = (const float*)d_in[0];
    const float* qkv_w  = (const float*)d_in[1];
    const float* qkv_b  = (const float*)d_in[2];
    const float* proj_w = (const float*)d_in[3];
    const float* proj_b = (const float*)d_in[4];
    float* out = (float*)d_out;

    char* ws = (char*)d_ws;
    unsigned short* qkv_bf = (unsigned short*)ws;
    unsigned short* xa_bf  = (unsigned short*)(ws + (size_t)MTOK * 1152 * 2);  // attn output
    unsigned short* qw_bf  = (unsigned short*)(ws + (size_t)MTOK * 1152 * 2 + (size_t)MTOK * DIM * 2);
    unsigned short* pw_bf  = qw_bf + 3 * DIM * DIM;

    cvt_w_kernel<<<(4 * DIM * DIM + 255) / 256, 256, 0, stream>>>(qkv_w, proj_w, qw_bf, pw_bf);

    // QKV: A = x (f32, fused cvt); grid (784 m-tiles) x (9 n-tiles), %8==0
    gemm_bt<true, true><<<(MTOK / 128) * 9, 256, 0, stream>>>(x, qw_bf, qkv_b, qkv_bf, 3 * DIM, 9);

    // attention: one block per (window, head-group of 4), 4 waves = 4 heads
    attn_mfma<<<2048 * 3, 256, 0, stream>>>(qkv_bf, xa_bf);

    // proj: A = attn out (bf16); grid (784 m-tiles) x (3 n-tiles), %8==0
    gemm_bt<false, false><<<(MTOK / 128) * 3, 256, 0, stream>>>(xa_bf, pw_bf, proj_b, out, DIM, 3);
}